// Round 4
// baseline (899.540 us; speedup 1.0000x reference)
//
#include <hip/hip_runtime.h>
#include <math.h>

// ---- problem sizes ----
constexpr int Bz = 32, Vz = 21, Dz = 512, Pz = 64;
constexpr int INz = Dz * Pz;         // 32768
constexpr int OUTz = 720;
constexpr int Ez = 8, Rz = 16, Hz = 256;
constexpr int Mz = Bz * Vz;          // 672
constexpr int Nz = OUTz + Ez * Rz;   // 848
constexpr int Kz = INz;

// ---- GEMM tiling ----
constexpr int BM = 128, BN = 128, BK = 32;
constexpr int SPLIT = 32;            // grid = 7*6*32 = 1344 blocks
constexpr int KSL = Kz / SPLIT;      // 1024
constexpr int NCH = KSL / BK;        // 32 chunks per block
constexpr int LDA = 40;              // LDS row stride in halves (80 B)

typedef _Float16 f16x8 __attribute__((ext_vector_type(8)));
typedef __fp16  fp16x2 __attribute__((ext_vector_type(2)));
typedef float f32x4 __attribute__((ext_vector_type(4)));

__device__ __forceinline__ unsigned int cvt2(float a, float b) {
    fp16x2 p = __builtin_amdgcn_cvt_pkrtz(a, b);
    return __builtin_bit_cast(unsigned int, p);
}

// ===================== fused GEMM (+pooling) =====================
// 256 threads = 4 waves (2x2 of 64x64 tiles); double-buffered LDS, 1 barrier/iter,
// depth-2 register prefetch; pooling via LDS, flushed once per block.
__global__ __launch_bounds__(256, 3)
void gemm_pool_kernel(const float* __restrict__ x, const float* __restrict__ Wb,
                      const float* __restrict__ lA, float* __restrict__ C,
                      float* __restrict__ pooled)
{
    __shared__ _Float16 As[2][BM * LDA];
    __shared__ _Float16 Bs[2][BN * LDA];
    __shared__ float plocal[BM][16];     // per-row K-slice pool partials (j = c>>1)

    const int nt = blockIdx.x;   // 0..6
    const int mt = blockIdx.y;   // 0..5
    const int s  = blockIdx.z;   // 0..31
    const int t  = threadIdx.x;  // 0..255
    const int r  = t >> 1;       // staged row 0..127
    const int h  = t & 1;        // 16-float half of the 32-wide chunk
    const int kbase = s * KSL + h * 16;

    int gm = mt * BM + r;
    const bool mval = (gm < Mz);
    if (!mval) gm = Mz - 1;
    const float* pa = x + (size_t)gm * Kz + kbase;

    int gn = nt * BN + r;
    if (gn >= Nz) gn = Nz - 1;
    const float* pb = (gn < OUTz) ? (Wb + (size_t)gn * Kz + kbase)
                                  : (lA + (size_t)(gn - OUTz) * Kz + kbase);

    const int wave = t >> 6, lane = t & 63;
    const int wr = (wave >> 1) * 64;
    const int wc = (wave & 1) * 64;
    const int fl = lane & 15;
    const int ko = (lane >> 4) * 8;

    f32x4 acc[4][4] = {};

    // depth-2 prefetch: two register sets
    float4 ca[2][4], cb[2][4];
    #pragma unroll
    for (int q = 0; q < 4; ++q) {
        ca[0][q] = *(const float4*)(pa + 4 * q);
        cb[0][q] = *(const float4*)(pb + 4 * q);
        ca[1][q] = *(const float4*)(pa + BK + 4 * q);
        cb[1][q] = *(const float4*)(pb + BK + 4 * q);
    }

    const bool do_pool = (nt == 0) && mval;
    float psum = 0.0f;

    for (int c = 0; c < NCH; ++c) {
        const int set = c & 1;
        if (do_pool) {   // this thread's 16 k all share one d-group
            psum += (ca[set][0].x + ca[set][0].y + ca[set][0].z + ca[set][0].w)
                  + (ca[set][1].x + ca[set][1].y + ca[set][1].z + ca[set][1].w)
                  + (ca[set][2].x + ca[set][2].y + ca[set][2].z + ca[set][2].w)
                  + (ca[set][3].x + ca[set][3].y + ca[set][3].z + ca[set][3].w);
        }
        if (c & 1) {     // flush pair: h-twin lanes are adjacent; single writer (h==0)
            float ps2 = psum + __shfl_down(psum, 1, 64);
            if (do_pool && h == 0) plocal[r][c >> 1] = ps2;
            psum = 0.0f;
        }

        _Float16* wA = &As[set][r * LDA + h * 16];
        *((uint4*)wA)     = make_uint4(cvt2(ca[set][0].x, ca[set][0].y), cvt2(ca[set][0].z, ca[set][0].w),
                                       cvt2(ca[set][1].x, ca[set][1].y), cvt2(ca[set][1].z, ca[set][1].w));
        *((uint4*)wA + 1) = make_uint4(cvt2(ca[set][2].x, ca[set][2].y), cvt2(ca[set][2].z, ca[set][2].w),
                                       cvt2(ca[set][3].x, ca[set][3].y), cvt2(ca[set][3].z, ca[set][3].w));
        _Float16* wB = &Bs[set][r * LDA + h * 16];
        *((uint4*)wB)     = make_uint4(cvt2(cb[set][0].x, cb[set][0].y), cvt2(cb[set][0].z, cb[set][0].w),
                                       cvt2(cb[set][1].x, cb[set][1].y), cvt2(cb[set][1].z, cb[set][1].w));
        *((uint4*)wB + 1) = make_uint4(cvt2(cb[set][2].x, cb[set][2].y), cvt2(cb[set][2].z, cb[set][2].w),
                                       cvt2(cb[set][3].x, cb[set][3].y), cvt2(cb[set][3].z, cb[set][3].w));

        if (c + 2 < NCH) {   // depth-2 prefetch into the set just consumed
            const float* qa = pa + (c + 2) * BK;
            const float* qb = pb + (c + 2) * BK;
            #pragma unroll
            for (int q = 0; q < 4; ++q) {
                ca[set][q] = *(const float4*)(qa + 4 * q);
                cb[set][q] = *(const float4*)(qb + 4 * q);
            }
        }
        __syncthreads();   // single barrier: write buf(set) -> read buf(set)

        f16x8 af[4], bfr[4];
        #pragma unroll
        for (int i = 0; i < 4; ++i)
            af[i] = *(const f16x8*)(&As[set][(wr + i * 16 + fl) * LDA + ko]);
        #pragma unroll
        for (int j = 0; j < 4; ++j)
            bfr[j] = *(const f16x8*)(&Bs[set][(wc + j * 16 + fl) * LDA + ko]);
        #pragma unroll
        for (int i = 0; i < 4; ++i)
            #pragma unroll
            for (int j = 0; j < 4; ++j)
                acc[i][j] = __builtin_amdgcn_mfma_f32_16x16x32_f16(af[i], bfr[j], acc[i][j], 0, 0, 0);
    }

    // pool flush: one global atomic per (row, d) pair, once per block
    if (nt == 0) {
        for (int idx = t; idx < BM * 16; idx += 256) {
            const int rr = idx >> 4, j = idx & 15;
            const int g = mt * BM + rr;
            if (g < Mz) atomicAdd(&pooled[(g / Vz) * Dz + s * 16 + j], plocal[rr][j]);
        }
    }

    // split-K epilogue: C/D layout col=lane&15, row=quad*4+reg
    const int rq = (lane >> 4) * 4;
    #pragma unroll
    for (int i = 0; i < 4; ++i) {
        const int gmr0 = mt * BM + wr + i * 16 + rq;
        #pragma unroll
        for (int j = 0; j < 4; ++j) {
            const int gnc = nt * BN + wc + j * 16 + fl;
            if (gnc < Nz) {
                #pragma unroll
                for (int q2 = 0; q2 < 4; ++q2) {
                    const int gmr = gmr0 + q2;
                    if (gmr < Mz) atomicAdd(&C[(size_t)gmr * Nz + gnc], acc[i][j][q2]);
                }
            }
        }
    }
}

// ===================== router =====================
__global__ __launch_bounds__(256)
void router_kernel(const float* __restrict__ pooled_raw,
                   const float* __restrict__ Wr1, const float* __restrict__ br1,
                   const float* __restrict__ Wr2, const float* __restrict__ br2,
                   float* __restrict__ probs_out, int* __restrict__ tki, float* __restrict__ tkw)
{
    const int b = blockIdx.x, t = threadIdx.x;
    const int wave = t >> 6, lane = t & 63;
    __shared__ float hbuf[Hz];
    __shared__ float lg[Ez];

    const float sc = 1.0f / (float)(Vz * Pz);
    float pv[8];
    const float* prow = pooled_raw + b * Dz + lane * 8;
    #pragma unroll
    for (int u = 0; u < 8; ++u) pv[u] = prow[u] * sc;

    for (int i0 = 0; i0 < 64; i0 += 4) {   // 4 rows in flight -> batched latency
        float v[4];
        #pragma unroll
        for (int u = 0; u < 4; ++u) {
            const int j = wave * 64 + i0 + u;
            const float* wrow = Wr1 + (size_t)j * Dz + lane * 8;
            float4 w0 = *(const float4*)(wrow);
            float4 w1 = *(const float4*)(wrow + 4);
            v[u] = pv[0]*w0.x + pv[1]*w0.y + pv[2]*w0.z + pv[3]*w0.w
                 + pv[4]*w1.x + pv[5]*w1.y + pv[6]*w1.z + pv[7]*w1.w;
        }
        #pragma unroll
        for (int u = 0; u < 4; ++u) {
            #pragma unroll
            for (int off = 32; off >= 1; off >>= 1) v[u] += __shfl_down(v[u], off, 64);
        }
        if (lane == 0) {
            #pragma unroll
            for (int u = 0; u < 4; ++u) {
                const int j = wave * 64 + i0 + u;
                float a = v[u] + br1[j];
                hbuf[j] = 0.5f * a * (1.0f + erff(a * 0.70710678118654752440f));
            }
        }
    }
    __syncthreads();

    if (t < Ez) {
        const float* w = Wr2 + (size_t)t * Hz;
        float a = br2[t];
        for (int j = 0; j < Hz; ++j) a = fmaf(hbuf[j], w[j], a);
        lg[t] = a;
    }
    __syncthreads();

    if (t == 0) {
        float mx = lg[0];
        for (int e = 1; e < Ez; ++e) mx = fmaxf(mx, lg[e]);
        float p[Ez], ssum = 0.0f;
        for (int e = 0; e < Ez; ++e) { p[e] = expf(lg[e] - mx); ssum += p[e]; }
        const float inv = 1.0f / ssum;
        for (int e = 0; e < Ez; ++e) { p[e] *= inv; probs_out[b * Ez + e] = p[e]; }
        int i0 = 0;
        for (int e = 1; e < Ez; ++e) if (p[e] > p[i0]) i0 = e;
        int i1 = (i0 == 0) ? 1 : 0;
        for (int e = 0; e < Ez; ++e) if (e != i0 && p[e] > p[i1]) i1 = e;
        float s2 = p[i0] + p[i1];
        if (s2 < 1e-6f) s2 = 1e-6f;
        tki[b * 2] = i0; tki[b * 2 + 1] = i1;
        tkw[b * 2] = p[i0] / s2; tkw[b * 2 + 1] = p[i1] / s2;
    }
}

// ===================== combine =====================
__global__ __launch_bounds__(256)
void combine_kernel(const float* __restrict__ C, const float* __restrict__ bb,
                    const float* __restrict__ loraB,
                    const int* __restrict__ tki, const float* __restrict__ tkw,
                    float* __restrict__ out)
{
    const int m = blockIdx.x;
    const int t = threadIdx.x;
    const int b = m / Vz;
    const int e0 = tki[b * 2], e1 = tki[b * 2 + 1];
    const float w0 = tkw[b * 2], w1 = tkw[b * 2 + 1];

    __shared__ float lw[2 * Rz];
    if (t < 2 * Rz) {
        const int e = (t < Rz) ? e0 : e1;
        lw[t] = C[(size_t)m * Nz + OUTz + e * Rz + (t & (Rz - 1))];
    }
    __syncthreads();

    for (int o = t; o < OUTz; o += 256) {
        float acc = C[(size_t)m * Nz + o] + bb[o];
        const float* B0 = loraB + ((size_t)e0 * OUTz + o) * Rz;
        const float* B1 = loraB + ((size_t)e1 * OUTz + o) * Rz;
        float d0 = 0.0f, d1 = 0.0f;
        #pragma unroll
        for (int rr = 0; rr < Rz; ++rr) {
            d0 = fmaf(lw[rr], B0[rr], d0);
            d1 = fmaf(lw[Rz + rr], B1[rr], d1);
        }
        out[(size_t)m * OUTz + o] = acc + w0 * d0 + w1 * d1;
    }
}

// ===================== launch =====================
extern "C" void kernel_launch(void* const* d_in, const int* in_sizes, int n_in,
                              void* d_out, int out_size, void* d_ws, size_t ws_size,
                              hipStream_t stream)
{
    const float* x   = (const float*)d_in[0];
    const float* Wb  = (const float*)d_in[1];
    const float* bb  = (const float*)d_in[2];
    const float* Wr1 = (const float*)d_in[3];
    const float* br1 = (const float*)d_in[4];
    const float* Wr2 = (const float*)d_in[5];
    const float* br2 = (const float*)d_in[6];
    const float* lA  = (const float*)d_in[7];
    const float* lB  = (const float*)d_in[8];
    float* out = (float*)d_out;

    float* C      = (float*)d_ws;            // 672*848 fp32
    float* pooled = C + (size_t)Mz * Nz;     // 32*512 fp32
    int*   tki    = (int*)(pooled + Bz * Dz);
    float* tkw    = (float*)(tki + 2 * Bz);

    (void)hipMemsetAsync(d_ws, 0, ((size_t)Mz * Nz + Bz * Dz) * sizeof(float), stream);

    gemm_pool_kernel<<<dim3(7, 6, SPLIT), 256, 0, stream>>>(x, Wb, lA, C, pooled);
    router_kernel<<<Bz, 256, 0, stream>>>(pooled, Wr1, br1, Wr2, br2,
                                          out + (size_t)Mz * OUTz, tki, tkw);
    combine_kernel<<<Mz, 256, 0, stream>>>(C, bb, lB, tki, tkw, out);
}

// Round 5
// 387.945 us; speedup vs baseline: 2.3187x; 2.3187x over previous
//
#include <hip/hip_runtime.h>
#include <math.h>

// ---- problem sizes ----
constexpr int Bz = 32, Vz = 21, Dz = 512, Pz = 64;
constexpr int INz = Dz * Pz;         // 32768
constexpr int OUTz = 720;
constexpr int Ez = 8, Rz = 16, Hz = 256;
constexpr int Mz = Bz * Vz;          // 672
constexpr int Nz = OUTz + Ez * Rz;   // 848
constexpr int Kz = INz;

// ---- GEMM tiling ----
constexpr int BM = 128, BN = 128, BK = 32;
constexpr int SPLIT = 32;            // grid = 7*6*32 = 1344 blocks
constexpr int KSL = Kz / SPLIT;      // 1024
constexpr int NCH = KSL / BK;        // 32 chunks per block (even)
constexpr int LDA = 40;              // LDS row stride in halves (80 B)

typedef _Float16 f16x8 __attribute__((ext_vector_type(8)));
typedef __fp16  fp16x2 __attribute__((ext_vector_type(2)));
typedef float f32x4 __attribute__((ext_vector_type(4)));

__device__ __forceinline__ unsigned int cvt2(float a, float b) {
    fp16x2 p = __builtin_amdgcn_cvt_pkrtz(a, b);
    return __builtin_bit_cast(unsigned int, p);
}

// ===================== fused GEMM (+pooling) =====================
// 256 threads = 4 waves (2x2 of 64x64 tiles); double-buffered LDS, 1 barrier/step,
// depth-2 register prefetch with COMPILE-TIME set index (macro-unrolled x2).
__global__ __launch_bounds__(256, 2)
void gemm_pool_kernel(const float* __restrict__ x, const float* __restrict__ Wb,
                      const float* __restrict__ lA, float* __restrict__ C,
                      float* __restrict__ pooled)
{
    __shared__ _Float16 As[2][BM * LDA];
    __shared__ _Float16 Bs[2][BN * LDA];
    __shared__ float plocal[BM][16];     // per-row K-slice pool partials (j = c>>1)

    const int nt = blockIdx.x;   // 0..6
    const int mt = blockIdx.y;   // 0..5
    const int s  = blockIdx.z;   // 0..31
    const int t  = threadIdx.x;  // 0..255
    const int r  = t >> 1;       // staged row 0..127
    const int h  = t & 1;        // 16-float half of the 32-wide chunk
    const int kbase = s * KSL + h * 16;

    int gm = mt * BM + r;
    const bool mval = (gm < Mz);
    if (!mval) gm = Mz - 1;
    const float* pa = x + (size_t)gm * Kz + kbase;

    int gn = nt * BN + r;
    if (gn >= Nz) gn = Nz - 1;
    const float* pb = (gn < OUTz) ? (Wb + (size_t)gn * Kz + kbase)
                                  : (lA + (size_t)(gn - OUTz) * Kz + kbase);

    const int wave = t >> 6, lane = t & 63;
    const int wr = (wave >> 1) * 64;
    const int wc = (wave & 1) * 64;
    const int fl = lane & 15;
    const int ko = (lane >> 4) * 8;

    f32x4 acc[4][4] = {};

    // depth-2 prefetch: two register sets, always indexed by LITERAL 0/1
    float4 ca[2][4], cb[2][4];
    #pragma unroll
    for (int q = 0; q < 4; ++q) {
        ca[0][q] = *(const float4*)(pa + 4 * q);
        cb[0][q] = *(const float4*)(pb + 4 * q);
        ca[1][q] = *(const float4*)(pa + BK + 4 * q);
        cb[1][q] = *(const float4*)(pb + BK + 4 * q);
    }

    const bool do_pool = (nt == 0) && mval;
    float psum = 0.0f;

#define GSTEP(SET, CIDX)                                                          \
    {                                                                             \
        const int c_ = (CIDX);                                                    \
        if (do_pool) {                                                            \
            psum += (ca[SET][0].x + ca[SET][0].y + ca[SET][0].z + ca[SET][0].w)   \
                  + (ca[SET][1].x + ca[SET][1].y + ca[SET][1].z + ca[SET][1].w)   \
                  + (ca[SET][2].x + ca[SET][2].y + ca[SET][2].z + ca[SET][2].w)   \
                  + (ca[SET][3].x + ca[SET][3].y + ca[SET][3].z + ca[SET][3].w);  \
        }                                                                         \
        if (SET == 1) {  /* flush pair: h-twin lanes adjacent; writer h==0 */     \
            float ps2 = psum + __shfl_down(psum, 1, 64);                          \
            if (do_pool && h == 0) plocal[r][c_ >> 1] = ps2;                      \
            psum = 0.0f;                                                          \
        }                                                                         \
        _Float16* wA = &As[SET][r * LDA + h * 16];                                \
        *((uint4*)wA)     = make_uint4(                                           \
            cvt2(ca[SET][0].x, ca[SET][0].y), cvt2(ca[SET][0].z, ca[SET][0].w),   \
            cvt2(ca[SET][1].x, ca[SET][1].y), cvt2(ca[SET][1].z, ca[SET][1].w));  \
        *((uint4*)wA + 1) = make_uint4(                                           \
            cvt2(ca[SET][2].x, ca[SET][2].y), cvt2(ca[SET][2].z, ca[SET][2].w),   \
            cvt2(ca[SET][3].x, ca[SET][3].y), cvt2(ca[SET][3].z, ca[SET][3].w));  \
        _Float16* wB = &Bs[SET][r * LDA + h * 16];                                \
        *((uint4*)wB)     = make_uint4(                                           \
            cvt2(cb[SET][0].x, cb[SET][0].y), cvt2(cb[SET][0].z, cb[SET][0].w),   \
            cvt2(cb[SET][1].x, cb[SET][1].y), cvt2(cb[SET][1].z, cb[SET][1].w));  \
        *((uint4*)wB + 1) = make_uint4(                                           \
            cvt2(cb[SET][2].x, cb[SET][2].y), cvt2(cb[SET][2].z, cb[SET][2].w),   \
            cvt2(cb[SET][3].x, cb[SET][3].y), cvt2(cb[SET][3].z, cb[SET][3].w));  \
        if (c_ + 2 < NCH) {   /* refill the set just consumed (depth-2) */        \
            const float* qa = pa + (c_ + 2) * BK;                                 \
            const float* qb = pb + (c_ + 2) * BK;                                 \
            _Pragma("unroll")                                                     \
            for (int q = 0; q < 4; ++q) {                                         \
                ca[SET][q] = *(const float4*)(qa + 4 * q);                        \
                cb[SET][q] = *(const float4*)(qb + 4 * q);                        \
            }                                                                     \
        }                                                                         \
        __syncthreads();                                                          \
        f16x8 af[4], bfr[4];                                                      \
        _Pragma("unroll")                                                         \
        for (int i = 0; i < 4; ++i)                                               \
            af[i] = *(const f16x8*)(&As[SET][(wr + i * 16 + fl) * LDA + ko]);     \
        _Pragma("unroll")                                                         \
        for (int j = 0; j < 4; ++j)                                               \
            bfr[j] = *(const f16x8*)(&Bs[SET][(wc + j * 16 + fl) * LDA + ko]);    \
        _Pragma("unroll")                                                         \
        for (int i = 0; i < 4; ++i)                                               \
            _Pragma("unroll")                                                     \
            for (int j = 0; j < 4; ++j)                                           \
                acc[i][j] = __builtin_amdgcn_mfma_f32_16x16x32_f16(               \
                                af[i], bfr[j], acc[i][j], 0, 0, 0);               \
    }

    for (int cc = 0; cc < NCH; cc += 2) {
        GSTEP(0, cc)
        GSTEP(1, cc + 1)
    }
#undef GSTEP

    // pool flush: one global atomic per (row, d) pair, once per block
    if (nt == 0) {
        for (int idx = t; idx < BM * 16; idx += 256) {
            const int rr = idx >> 4, j = idx & 15;
            const int g = mt * BM + rr;
            if (g < Mz) atomicAdd(&pooled[(g / Vz) * Dz + s * 16 + j], plocal[rr][j]);
        }
    }

    // split-K epilogue: C/D layout col=lane&15, row=quad*4+reg
    const int rq = (lane >> 4) * 4;
    #pragma unroll
    for (int i = 0; i < 4; ++i) {
        const int gmr0 = mt * BM + wr + i * 16 + rq;
        #pragma unroll
        for (int j = 0; j < 4; ++j) {
            const int gnc = nt * BN + wc + j * 16 + fl;
            if (gnc < Nz) {
                #pragma unroll
                for (int q2 = 0; q2 < 4; ++q2) {
                    const int gmr = gmr0 + q2;
                    if (gmr < Mz) atomicAdd(&C[(size_t)gmr * Nz + gnc], acc[i][j][q2]);
                }
            }
        }
    }
}

// ===================== router =====================
__global__ __launch_bounds__(256)
void router_kernel(const float* __restrict__ pooled_raw,
                   const float* __restrict__ Wr1, const float* __restrict__ br1,
                   const float* __restrict__ Wr2, const float* __restrict__ br2,
                   float* __restrict__ probs_out, int* __restrict__ tki, float* __restrict__ tkw)
{
    const int b = blockIdx.x, t = threadIdx.x;
    const int wave = t >> 6, lane = t & 63;
    __shared__ float hbuf[Hz];
    __shared__ float lg[Ez];

    const float sc = 1.0f / (float)(Vz * Pz);
    float pv[8];
    const float* prow = pooled_raw + b * Dz + lane * 8;
    #pragma unroll
    for (int u = 0; u < 8; ++u) pv[u] = prow[u] * sc;

    for (int i0 = 0; i0 < 64; i0 += 4) {
        float v[4];
        #pragma unroll
        for (int u = 0; u < 4; ++u) {
            const int j = wave * 64 + i0 + u;
            const float* wrow = Wr1 + (size_t)j * Dz + lane * 8;
            float4 w0 = *(const float4*)(wrow);
            float4 w1 = *(const float4*)(wrow + 4);
            v[u] = pv[0]*w0.x + pv[1]*w0.y + pv[2]*w0.z + pv[3]*w0.w
                 + pv[4]*w1.x + pv[5]*w1.y + pv[6]*w1.z + pv[7]*w1.w;
        }
        #pragma unroll
        for (int u = 0; u < 4; ++u) {
            #pragma unroll
            for (int off = 32; off >= 1; off >>= 1) v[u] += __shfl_down(v[u], off, 64);
        }
        if (lane == 0) {
            #pragma unroll
            for (int u = 0; u < 4; ++u) {
                const int j = wave * 64 + i0 + u;
                float a = v[u] + br1[j];
                hbuf[j] = 0.5f * a * (1.0f + erff(a * 0.70710678118654752440f));
            }
        }
    }
    __syncthreads();

    if (t < Ez) {
        const float* w = Wr2 + (size_t)t * Hz;
        float a = br2[t];
        for (int j = 0; j < Hz; ++j) a = fmaf(hbuf[j], w[j], a);
        lg[t] = a;
    }
    __syncthreads();

    if (t == 0) {
        float mx = lg[0];
        for (int e = 1; e < Ez; ++e) mx = fmaxf(mx, lg[e]);
        float p[Ez], ssum = 0.0f;
        for (int e = 0; e < Ez; ++e) { p[e] = expf(lg[e] - mx); ssum += p[e]; }
        const float inv = 1.0f / ssum;
        for (int e = 0; e < Ez; ++e) { p[e] *= inv; probs_out[b * Ez + e] = p[e]; }
        int i0 = 0;
        for (int e = 1; e < Ez; ++e) if (p[e] > p[i0]) i0 = e;
        int i1 = (i0 == 0) ? 1 : 0;
        for (int e = 0; e < Ez; ++e) if (e != i0 && p[e] > p[i1]) i1 = e;
        float s2 = p[i0] + p[i1];
        if (s2 < 1e-6f) s2 = 1e-6f;
        tki[b * 2] = i0; tki[b * 2 + 1] = i1;
        tkw[b * 2] = p[i0] / s2; tkw[b * 2 + 1] = p[i1] / s2;
    }
}

// ===================== combine =====================
__global__ __launch_bounds__(256)
void combine_kernel(const float* __restrict__ C, const float* __restrict__ bb,
                    const float* __restrict__ loraB,
                    const int* __restrict__ tki, const float* __restrict__ tkw,
                    float* __restrict__ out)
{
    const int m = blockIdx.x;
    const int t = threadIdx.x;
    const int b = m / Vz;
    const int e0 = tki[b * 2], e1 = tki[b * 2 + 1];
    const float w0 = tkw[b * 2], w1 = tkw[b * 2 + 1];

    __shared__ float lw[2 * Rz];
    if (t < 2 * Rz) {
        const int e = (t < Rz) ? e0 : e1;
        lw[t] = C[(size_t)m * Nz + OUTz + e * Rz + (t & (Rz - 1))];
    }
    __syncthreads();

    for (int o = t; o < OUTz; o += 256) {
        float acc = C[(size_t)m * Nz + o] + bb[o];
        const float* B0 = loraB + ((size_t)e0 * OUTz + o) * Rz;
        const float* B1 = loraB + ((size_t)e1 * OUTz + o) * Rz;
        float d0 = 0.0f, d1 = 0.0f;
        #pragma unroll
        for (int rr = 0; rr < Rz; ++rr) {
            d0 = fmaf(lw[rr], B0[rr], d0);
            d1 = fmaf(lw[Rz + rr], B1[rr], d1);
        }
        out[(size_t)m * OUTz + o] = acc + w0 * d0 + w1 * d1;
    }
}

// ===================== launch =====================
extern "C" void kernel_launch(void* const* d_in, const int* in_sizes, int n_in,
                              void* d_out, int out_size, void* d_ws, size_t ws_size,
                              hipStream_t stream)
{
    const float* x   = (const float*)d_in[0];
    const float* Wb  = (const float*)d_in[1];
    const float* bb  = (const float*)d_in[2];
    const float* Wr1 = (const float*)d_in[3];
    const float* br1 = (const float*)d_in[4];
    const float* Wr2 = (const float*)d_in[5];
    const float* br2 = (const float*)d_in[6];
    const float* lA  = (const float*)d_in[7];
    const float* lB  = (const float*)d_in[8];
    float* out = (float*)d_out;

    float* C      = (float*)d_ws;            // 672*848 fp32
    float* pooled = C + (size_t)Mz * Nz;     // 32*512 fp32
    int*   tki    = (int*)(pooled + Bz * Dz);
    float* tkw    = (float*)(tki + 2 * Bz);

    (void)hipMemsetAsync(d_ws, 0, ((size_t)Mz * Nz + Bz * Dz) * sizeof(float), stream);

    gemm_pool_kernel<<<dim3(7, 6, SPLIT), 256, 0, stream>>>(x, Wb, lA, C, pooled);
    router_kernel<<<Bz, 256, 0, stream>>>(pooled, Wr1, br1, Wr2, br2,
                                          out + (size_t)Mz * OUTz, tki, tkw);
    combine_kernel<<<Mz, 256, 0, stream>>>(C, bb, lB, tki, tkw, out);
}

// Round 6
// 377.002 us; speedup vs baseline: 2.3860x; 1.0290x over previous
//
#include <hip/hip_runtime.h>
#include <math.h>

// ---- problem sizes ----
constexpr int Bz = 32, Vz = 21, Dz = 512, Pz = 64;
constexpr int INz = Dz * Pz;         // 32768
constexpr int OUTz = 720;
constexpr int Ez = 8, Rz = 16, Hz = 256;
constexpr int Mz = Bz * Vz;          // 672
constexpr int Nz = OUTz + Ez * Rz;   // 848
constexpr int Kz = INz;

// ---- GEMM tiling ----
constexpr int BM = 128, BN = 128, BK = 32;
constexpr int SPLIT = 32;            // 7*6*32 = 1344 blocks
constexpr int KSL = Kz / SPLIT;      // 1024
constexpr int NCH = KSL / BK;        // 32 chunks per block (even)
constexpr int LDA = 40;              // LDS row stride in halves (80 B)

typedef _Float16 f16x8 __attribute__((ext_vector_type(8)));
typedef __fp16  fp16x2 __attribute__((ext_vector_type(2)));
typedef float f32x4 __attribute__((ext_vector_type(4)));

__device__ __forceinline__ unsigned int cvt2(float a, float b) {
    fp16x2 p = __builtin_amdgcn_cvt_pkrtz(a, b);
    return __builtin_bit_cast(unsigned int, p);
}

// barrier that drains ONLY lds/smem counters — global prefetch stays in flight.
// Correctness: ds_writes visible to other waves (lgkmcnt(0) + barrier); each
// wave's ds_reads of the current buffer are also covered by lgkmcnt(0) before
// it can pass the next barrier, so single-barrier double-buffering is safe.
__device__ __forceinline__ void barrier_lgkm() {
    asm volatile("s_waitcnt lgkmcnt(0)\n\ts_barrier" ::: "memory");
}

// ===================== fused GEMM (+pooling) =====================
// 256 threads = 4 waves (2x2 of 64x64 tiles); double-buffered LDS, 1 lgkm-barrier/step,
// depth-2 register prefetch (compile-time set index), XCD-cohort swizzled grid.
__global__ __launch_bounds__(256, 3)
void gemm_pool_kernel(const float* __restrict__ x, const float* __restrict__ Wb,
                      const float* __restrict__ lA, float* __restrict__ C,
                      float* __restrict__ pooled)
{
    __shared__ _Float16 As[2][BM * LDA];
    __shared__ _Float16 Bs[2][BN * LDA];
    __shared__ float plocal[BM][16];

    // swizzle: id%8 == s%8 -> all blocks of one K-slice land on one XCD cohort
    const int id = blockIdx.x;       // 0..1343
    const int x8 = id & 7;
    const int k8 = id >> 3;          // 0..167
    const int nt = k8 % 7;
    const int mt = (k8 / 7) % 6;
    const int s  = (k8 / 42) * 8 + x8;   // 0..31

    const int t  = threadIdx.x;  // 0..255
    const int r  = t >> 1;       // staged row 0..127
    const int h  = t & 1;        // 16-float half of the 32-wide chunk
    const int kbase = s * KSL + h * 16;

    int gm = mt * BM + r;
    const bool mval = (gm < Mz);
    if (!mval) gm = Mz - 1;
    const float* pa = x + (size_t)gm * Kz + kbase;

    int gn = nt * BN + r;
    if (gn >= Nz) gn = Nz - 1;
    const float* pb = (gn < OUTz) ? (Wb + (size_t)gn * Kz + kbase)
                                  : (lA + (size_t)(gn - OUTz) * Kz + kbase);

    const int wave = t >> 6, lane = t & 63;
    const int wr = (wave >> 1) * 64;
    const int wc = (wave & 1) * 64;
    const int fl = lane & 15;
    const int ko = (lane >> 4) * 8;

    f32x4 acc[4][4] = {};

    // depth-2 prefetch: two register sets, always indexed by LITERAL 0/1
    float4 ca[2][4], cb[2][4];
    #pragma unroll
    for (int q = 0; q < 4; ++q) {
        ca[0][q] = *(const float4*)(pa + 4 * q);
        cb[0][q] = *(const float4*)(pb + 4 * q);
        ca[1][q] = *(const float4*)(pa + BK + 4 * q);
        cb[1][q] = *(const float4*)(pb + BK + 4 * q);
    }

    const bool do_pool = (nt == 0) && mval;
    float psum = 0.0f;

#define GSTEP(SET, CIDX)                                                          \
    {                                                                             \
        const int c_ = (CIDX);                                                    \
        if (do_pool) {                                                            \
            psum += (ca[SET][0].x + ca[SET][0].y + ca[SET][0].z + ca[SET][0].w)   \
                  + (ca[SET][1].x + ca[SET][1].y + ca[SET][1].z + ca[SET][1].w)   \
                  + (ca[SET][2].x + ca[SET][2].y + ca[SET][2].z + ca[SET][2].w)   \
                  + (ca[SET][3].x + ca[SET][3].y + ca[SET][3].z + ca[SET][3].w);  \
        }                                                                         \
        if (SET == 1) {                                                           \
            float ps2 = psum + __shfl_down(psum, 1, 64);                          \
            if (do_pool && h == 0) plocal[r][c_ >> 1] = ps2;                      \
            psum = 0.0f;                                                          \
        }                                                                         \
        _Float16* wA = &As[SET][r * LDA + h * 16];                                \
        *((uint4*)wA)     = make_uint4(                                           \
            cvt2(ca[SET][0].x, ca[SET][0].y), cvt2(ca[SET][0].z, ca[SET][0].w),   \
            cvt2(ca[SET][1].x, ca[SET][1].y), cvt2(ca[SET][1].z, ca[SET][1].w));  \
        *((uint4*)wA + 1) = make_uint4(                                           \
            cvt2(ca[SET][2].x, ca[SET][2].y), cvt2(ca[SET][2].z, ca[SET][2].w),   \
            cvt2(ca[SET][3].x, ca[SET][3].y), cvt2(ca[SET][3].z, ca[SET][3].w));  \
        _Float16* wB = &Bs[SET][r * LDA + h * 16];                                \
        *((uint4*)wB)     = make_uint4(                                           \
            cvt2(cb[SET][0].x, cb[SET][0].y), cvt2(cb[SET][0].z, cb[SET][0].w),   \
            cvt2(cb[SET][1].x, cb[SET][1].y), cvt2(cb[SET][1].z, cb[SET][1].w));  \
        *((uint4*)wB + 1) = make_uint4(                                           \
            cvt2(cb[SET][2].x, cb[SET][2].y), cvt2(cb[SET][2].z, cb[SET][2].w),   \
            cvt2(cb[SET][3].x, cb[SET][3].y), cvt2(cb[SET][3].z, cb[SET][3].w));  \
        if (c_ + 2 < NCH) {   /* refill the set just consumed (depth-2) */        \
            const float* qa = pa + (c_ + 2) * BK;                                 \
            const float* qb = pb + (c_ + 2) * BK;                                 \
            _Pragma("unroll")                                                     \
            for (int q = 0; q < 4; ++q) {                                         \
                ca[SET][q] = *(const float4*)(qa + 4 * q);                        \
                cb[SET][q] = *(const float4*)(qb + 4 * q);                        \
            }                                                                     \
        }                                                                         \
        barrier_lgkm();                                                           \
        f16x8 af[4], bfr[4];                                                      \
        _Pragma("unroll")                                                         \
        for (int i = 0; i < 4; ++i)                                               \
            af[i] = *(const f16x8*)(&As[SET][(wr + i * 16 + fl) * LDA + ko]);     \
        _Pragma("unroll")                                                         \
        for (int j = 0; j < 4; ++j)                                               \
            bfr[j] = *(const f16x8*)(&Bs[SET][(wc + j * 16 + fl) * LDA + ko]);    \
        _Pragma("unroll")                                                         \
        for (int i = 0; i < 4; ++i)                                               \
            _Pragma("unroll")                                                     \
            for (int j = 0; j < 4; ++j)                                           \
                acc[i][j] = __builtin_amdgcn_mfma_f32_16x16x32_f16(               \
                                af[i], bfr[j], acc[i][j], 0, 0, 0);               \
    }

    for (int cc = 0; cc < NCH; cc += 2) {
        GSTEP(0, cc)
        GSTEP(1, cc + 1)
    }
#undef GSTEP

    // pool flush: one global atomic per (row, d) pair, once per block
    if (nt == 0) {
        __syncthreads();   // full barrier before cross-thread plocal reads
        for (int idx = t; idx < BM * 16; idx += 256) {
            const int rr = idx >> 4, j = idx & 15;
            const int g = mt * BM + rr;
            if (g < Mz) atomicAdd(&pooled[(g / Vz) * Dz + s * 16 + j], plocal[rr][j]);
        }
    }

    // split-K epilogue: C/D layout col=lane&15, row=quad*4+reg
    const int rq = (lane >> 4) * 4;
    #pragma unroll
    for (int i = 0; i < 4; ++i) {
        const int gmr0 = mt * BM + wr + i * 16 + rq;
        #pragma unroll
        for (int j = 0; j < 4; ++j) {
            const int gnc = nt * BN + wc + j * 16 + fl;
            if (gnc < Nz) {
                #pragma unroll
                for (int q2 = 0; q2 < 4; ++q2) {
                    const int gmr = gmr0 + q2;
                    if (gmr < Mz) atomicAdd(&C[(size_t)gmr * Nz + gnc], acc[i][j][q2]);
                }
            }
        }
    }
}

// ===================== router =====================
__global__ __launch_bounds__(256)
void router_kernel(const float* __restrict__ pooled_raw,
                   const float* __restrict__ Wr1, const float* __restrict__ br1,
                   const float* __restrict__ Wr2, const float* __restrict__ br2,
                   float* __restrict__ probs_out, int* __restrict__ tki, float* __restrict__ tkw)
{
    const int b = blockIdx.x, t = threadIdx.x;
    const int wave = t >> 6, lane = t & 63;
    __shared__ float hbuf[Hz];
    __shared__ float lg[Ez];

    const float sc = 1.0f / (float)(Vz * Pz);
    float pv[8];
    const float* prow = pooled_raw + b * Dz + lane * 8;
    #pragma unroll
    for (int u = 0; u < 8; ++u) pv[u] = prow[u] * sc;

    for (int i0 = 0; i0 < 64; i0 += 4) {
        float v[4];
        #pragma unroll
        for (int u = 0; u < 4; ++u) {
            const int j = wave * 64 + i0 + u;
            const float* wrow = Wr1 + (size_t)j * Dz + lane * 8;
            float4 w0 = *(const float4*)(wrow);
            float4 w1 = *(const float4*)(wrow + 4);
            v[u] = pv[0]*w0.x + pv[1]*w0.y + pv[2]*w0.z + pv[3]*w0.w
                 + pv[4]*w1.x + pv[5]*w1.y + pv[6]*w1.z + pv[7]*w1.w;
        }
        #pragma unroll
        for (int u = 0; u < 4; ++u) {
            #pragma unroll
            for (int off = 32; off >= 1; off >>= 1) v[u] += __shfl_down(v[u], off, 64);
        }
        if (lane == 0) {
            #pragma unroll
            for (int u = 0; u < 4; ++u) {
                const int j = wave * 64 + i0 + u;
                float a = v[u] + br1[j];
                hbuf[j] = 0.5f * a * (1.0f + erff(a * 0.70710678118654752440f));
            }
        }
    }
    __syncthreads();

    if (t < Ez) {
        const float* w = Wr2 + (size_t)t * Hz;
        float a = br2[t];
        for (int j = 0; j < Hz; ++j) a = fmaf(hbuf[j], w[j], a);
        lg[t] = a;
    }
    __syncthreads();

    if (t == 0) {
        float mx = lg[0];
        for (int e = 1; e < Ez; ++e) mx = fmaxf(mx, lg[e]);
        float p[Ez], ssum = 0.0f;
        for (int e = 0; e < Ez; ++e) { p[e] = expf(lg[e] - mx); ssum += p[e]; }
        const float inv = 1.0f / ssum;
        for (int e = 0; e < Ez; ++e) { p[e] *= inv; probs_out[b * Ez + e] = p[e]; }
        int i0 = 0;
        for (int e = 1; e < Ez; ++e) if (p[e] > p[i0]) i0 = e;
        int i1 = (i0 == 0) ? 1 : 0;
        for (int e = 0; e < Ez; ++e) if (e != i0 && p[e] > p[i1]) i1 = e;
        float s2 = p[i0] + p[i1];
        if (s2 < 1e-6f) s2 = 1e-6f;
        tki[b * 2] = i0; tki[b * 2 + 1] = i1;
        tkw[b * 2] = p[i0] / s2; tkw[b * 2 + 1] = p[i1] / s2;
    }
}

// ===================== combine =====================
__global__ __launch_bounds__(256)
void combine_kernel(const float* __restrict__ C, const float* __restrict__ bb,
                    const float* __restrict__ loraB,
                    const int* __restrict__ tki, const float* __restrict__ tkw,
                    float* __restrict__ out)
{
    const int m = blockIdx.x;
    const int t = threadIdx.x;
    const int b = m / Vz;
    const int e0 = tki[b * 2], e1 = tki[b * 2 + 1];
    const float w0 = tkw[b * 2], w1 = tkw[b * 2 + 1];

    __shared__ float lw[2 * Rz];
    if (t < 2 * Rz) {
        const int e = (t < Rz) ? e0 : e1;
        lw[t] = C[(size_t)m * Nz + OUTz + e * Rz + (t & (Rz - 1))];
    }
    __syncthreads();

    for (int o = t; o < OUTz; o += 256) {
        float acc = C[(size_t)m * Nz + o] + bb[o];
        const float* B0 = loraB + ((size_t)e0 * OUTz + o) * Rz;
        const float* B1 = loraB + ((size_t)e1 * OUTz + o) * Rz;
        float d0 = 0.0f, d1 = 0.0f;
        #pragma unroll
        for (int rr = 0; rr < Rz; ++rr) {
            d0 = fmaf(lw[rr], B0[rr], d0);
            d1 = fmaf(lw[Rz + rr], B1[rr], d1);
        }
        out[(size_t)m * OUTz + o] = acc + w0 * d0 + w1 * d1;
    }
}

// ===================== launch =====================
extern "C" void kernel_launch(void* const* d_in, const int* in_sizes, int n_in,
                              void* d_out, int out_size, void* d_ws, size_t ws_size,
                              hipStream_t stream)
{
    const float* x   = (const float*)d_in[0];
    const float* Wb  = (const float*)d_in[1];
    const float* bb  = (const float*)d_in[2];
    const float* Wr1 = (const float*)d_in[3];
    const float* br1 = (const float*)d_in[4];
    const float* Wr2 = (const float*)d_in[5];
    const float* br2 = (const float*)d_in[6];
    const float* lA  = (const float*)d_in[7];
    const float* lB  = (const float*)d_in[8];
    float* out = (float*)d_out;

    float* C      = (float*)d_ws;            // 672*848 fp32
    float* pooled = C + (size_t)Mz * Nz;     // 32*512 fp32
    int*   tki    = (int*)(pooled + Bz * Dz);
    float* tkw    = (float*)(tki + 2 * Bz);

    (void)hipMemsetAsync(d_ws, 0, ((size_t)Mz * Nz + Bz * Dz) * sizeof(float), stream);

    gemm_pool_kernel<<<dim3(7 * 6 * SPLIT), 256, 0, stream>>>(x, Wb, lA, C, pooled);
    router_kernel<<<Bz, 256, 0, stream>>>(pooled, Wr1, br1, Wr2, br2,
                                          out + (size_t)Mz * OUTz, tki, tkw);
    combine_kernel<<<Mz, 256, 0, stream>>>(C, bb, lB, tki, tkw, out);
}

// Round 7
// 362.798 us; speedup vs baseline: 2.4795x; 1.0392x over previous
//
#include <hip/hip_runtime.h>
#include <math.h>

// ---- problem sizes ----
constexpr int Bz = 32, Vz = 21, Dz = 512, Pz = 64;
constexpr int INz = Dz * Pz;         // 32768
constexpr int OUTz = 720;
constexpr int Ez = 8, Rz = 16, Hz = 256;
constexpr int Mz = Bz * Vz;          // 672
constexpr int Nz = OUTz + Ez * Rz;   // 848
constexpr int Kz = INz;

// ---- GEMM tiling ----
constexpr int BM = 128, BN = 128, BK = 32;
constexpr int SPLIT = 16;            // 7*6*16 = 672 blocks
constexpr int KSL = Kz / SPLIT;      // 2048
constexpr int NCH = KSL / BK;        // 64 chunks per block (even)
constexpr int LDA = 36;              // LDS row stride in halves (72 B = 18 banks, gcd(18,32)=2)

typedef _Float16 f16x8 __attribute__((ext_vector_type(8)));
typedef __fp16  fp16x2 __attribute__((ext_vector_type(2)));
typedef float f32x4 __attribute__((ext_vector_type(4)));

__device__ __forceinline__ unsigned int cvt2(float a, float b) {
    fp16x2 p = __builtin_amdgcn_cvt_pkrtz(a, b);
    return __builtin_bit_cast(unsigned int, p);
}

// barrier draining only lds counters — global prefetch loads stay in flight
__device__ __forceinline__ void barrier_lgkm() {
    asm volatile("s_waitcnt lgkmcnt(0)\n\ts_barrier" ::: "memory");
}

// ===================== fused GEMM (+pooling) =====================
// 256 threads = 4 waves (2x2 of 64x64); double-buffered LDS, 1 lgkm-barrier/step,
// depth-2 register prefetch; XCD-cohort swizzle; split-K partials via PLAIN STORES
// (PART=true) or atomic fallback (PART=false) if workspace is small.
template <bool PART>
__global__ __launch_bounds__(256, 3)
void gemm_pool_kernel(const float* __restrict__ x, const float* __restrict__ Wb,
                      const float* __restrict__ lA, float* __restrict__ part,
                      float* __restrict__ C, float* __restrict__ pooled)
{
    __shared__ _Float16 As[2][BM * LDA];
    __shared__ _Float16 Bs[2][BN * LDA];
    __shared__ float plocal[BM][NCH / 2];    // 128 x 32 = 16 KB

    // swizzle: id%8 == s%8 -> one K-slice's blocks form an XCD cohort
    const int id = blockIdx.x;       // 0..671
    const int x8 = id & 7;
    const int k8 = id >> 3;          // 0..83
    const int nt = k8 % 7;
    const int mt = (k8 / 7) % 6;
    const int s  = (k8 / 42) * 8 + x8;   // 0..15

    const int t  = threadIdx.x;  // 0..255
    const int r  = t >> 1;       // staged row 0..127
    const int h  = t & 1;        // 16-float half of the 32-wide chunk
    const int kbase = s * KSL + h * 16;

    int gm = mt * BM + r;
    const bool mval = (gm < Mz);
    if (!mval) gm = Mz - 1;
    const float* pa = x + (size_t)gm * Kz + kbase;

    int gn = nt * BN + r;
    if (gn >= Nz) gn = Nz - 1;
    const float* pb = (gn < OUTz) ? (Wb + (size_t)gn * Kz + kbase)
                                  : (lA + (size_t)(gn - OUTz) * Kz + kbase);

    const int wave = t >> 6, lane = t & 63;
    const int wr = (wave >> 1) * 64;
    const int wc = (wave & 1) * 64;
    const int fl = lane & 15;
    const int ko = (lane >> 4) * 8;

    f32x4 acc[4][4] = {};

    float4 ca[2][4], cb[2][4];
    #pragma unroll
    for (int q = 0; q < 4; ++q) {
        ca[0][q] = *(const float4*)(pa + 4 * q);
        cb[0][q] = *(const float4*)(pb + 4 * q);
        ca[1][q] = *(const float4*)(pa + BK + 4 * q);
        cb[1][q] = *(const float4*)(pb + BK + 4 * q);
    }

    const bool do_pool = (nt == 0) && mval;
    float psum = 0.0f;

#define GSTEP(SET, CIDX)                                                          \
    {                                                                             \
        const int c_ = (CIDX);                                                    \
        if (do_pool) {                                                            \
            psum += (ca[SET][0].x + ca[SET][0].y + ca[SET][0].z + ca[SET][0].w)   \
                  + (ca[SET][1].x + ca[SET][1].y + ca[SET][1].z + ca[SET][1].w)   \
                  + (ca[SET][2].x + ca[SET][2].y + ca[SET][2].z + ca[SET][2].w)   \
                  + (ca[SET][3].x + ca[SET][3].y + ca[SET][3].z + ca[SET][3].w);  \
        }                                                                         \
        if (SET == 1) {  /* c even/odd pair shares one d-group of 64 k */         \
            float ps2 = psum + __shfl_down(psum, 1, 64);                          \
            if (do_pool && h == 0) plocal[r][c_ >> 1] = ps2;                      \
            psum = 0.0f;                                                          \
        }                                                                         \
        _Float16* wA = &As[SET][r * LDA + h * 16];                                \
        *((uint4*)wA)     = make_uint4(                                           \
            cvt2(ca[SET][0].x, ca[SET][0].y), cvt2(ca[SET][0].z, ca[SET][0].w),   \
            cvt2(ca[SET][1].x, ca[SET][1].y), cvt2(ca[SET][1].z, ca[SET][1].w));  \
        *((uint4*)wA + 1) = make_uint4(                                           \
            cvt2(ca[SET][2].x, ca[SET][2].y), cvt2(ca[SET][2].z, ca[SET][2].w),   \
            cvt2(ca[SET][3].x, ca[SET][3].y), cvt2(ca[SET][3].z, ca[SET][3].w));  \
        _Float16* wB = &Bs[SET][r * LDA + h * 16];                                \
        *((uint4*)wB)     = make_uint4(                                           \
            cvt2(cb[SET][0].x, cb[SET][0].y), cvt2(cb[SET][0].z, cb[SET][0].w),   \
            cvt2(cb[SET][1].x, cb[SET][1].y), cvt2(cb[SET][1].z, cb[SET][1].w));  \
        *((uint4*)wB + 1) = make_uint4(                                           \
            cvt2(cb[SET][2].x, cb[SET][2].y), cvt2(cb[SET][2].z, cb[SET][2].w),   \
            cvt2(cb[SET][3].x, cb[SET][3].y), cvt2(cb[SET][3].z, cb[SET][3].w));  \
        if (c_ + 2 < NCH) {                                                       \
            const float* qa = pa + (c_ + 2) * BK;                                 \
            const float* qb = pb + (c_ + 2) * BK;                                 \
            _Pragma("unroll")                                                     \
            for (int q = 0; q < 4; ++q) {                                         \
                ca[SET][q] = *(const float4*)(qa + 4 * q);                        \
                cb[SET][q] = *(const float4*)(qb + 4 * q);                        \
            }                                                                     \
        }                                                                         \
        barrier_lgkm();                                                           \
        f16x8 af[4], bfr[4];                                                      \
        _Pragma("unroll")                                                         \
        for (int i = 0; i < 4; ++i)                                               \
            af[i] = *(const f16x8*)(&As[SET][(wr + i * 16 + fl) * LDA + ko]);     \
        _Pragma("unroll")                                                         \
        for (int j = 0; j < 4; ++j)                                               \
            bfr[j] = *(const f16x8*)(&Bs[SET][(wc + j * 16 + fl) * LDA + ko]);    \
        _Pragma("unroll")                                                         \
        for (int i = 0; i < 4; ++i)                                               \
            _Pragma("unroll")                                                     \
            for (int j = 0; j < 4; ++j)                                           \
                acc[i][j] = __builtin_amdgcn_mfma_f32_16x16x32_f16(               \
                                af[i], bfr[j], acc[i][j], 0, 0, 0);               \
    }

    for (int cc = 0; cc < NCH; cc += 2) {
        GSTEP(0, cc)
        GSTEP(1, cc + 1)
    }
#undef GSTEP

    // pool flush: one global atomic per (row, d-group), once per block
    if (nt == 0) {
        __syncthreads();
        for (int idx = t; idx < BM * (NCH / 2); idx += 256) {
            const int rr = idx / (NCH / 2), j = idx % (NCH / 2);
            const int g = mt * BM + rr;
            if (g < Mz) atomicAdd(&pooled[(g / Vz) * Dz + s * (NCH / 2) + j], plocal[rr][j]);
        }
    }

    // split-K epilogue.  C/D layout: col=lane&15, row=quad*4+reg
    const int rq = (lane >> 4) * 4;
    float* dst = PART ? (part + (size_t)s * Mz * Nz) : C;
    #pragma unroll
    for (int i = 0; i < 4; ++i) {
        const int gmr0 = mt * BM + wr + i * 16 + rq;
        #pragma unroll
        for (int j = 0; j < 4; ++j) {
            const int gnc = nt * BN + wc + j * 16 + fl;
            if (gnc < Nz) {
                #pragma unroll
                for (int q2 = 0; q2 < 4; ++q2) {
                    const int gmr = gmr0 + q2;
                    if (gmr < Mz) {
                        if (PART) dst[(size_t)gmr * Nz + gnc] = acc[i][j][q2];
                        else      atomicAdd(&dst[(size_t)gmr * Nz + gnc], acc[i][j][q2]);
                    }
                }
            }
        }
    }
}

// ===================== router =====================
__global__ __launch_bounds__(256)
void router_kernel(const float* __restrict__ pooled_raw,
                   const float* __restrict__ Wr1, const float* __restrict__ br1,
                   const float* __restrict__ Wr2, const float* __restrict__ br2,
                   float* __restrict__ probs_out, int* __restrict__ tki, float* __restrict__ tkw)
{
    const int b = blockIdx.x, t = threadIdx.x;
    const int wave = t >> 6, lane = t & 63;
    __shared__ float hbuf[Hz];
    __shared__ float lg[Ez];

    const float sc = 1.0f / (float)(Vz * Pz);
    float pv[8];
    const float* prow = pooled_raw + b * Dz + lane * 8;
    #pragma unroll
    for (int u = 0; u < 8; ++u) pv[u] = prow[u] * sc;

    for (int i0 = 0; i0 < 64; i0 += 4) {
        float v[4];
        #pragma unroll
        for (int u = 0; u < 4; ++u) {
            const int j = wave * 64 + i0 + u;
            const float* wrow = Wr1 + (size_t)j * Dz + lane * 8;
            float4 w0 = *(const float4*)(wrow);
            float4 w1 = *(const float4*)(wrow + 4);
            v[u] = pv[0]*w0.x + pv[1]*w0.y + pv[2]*w0.z + pv[3]*w0.w
                 + pv[4]*w1.x + pv[5]*w1.y + pv[6]*w1.z + pv[7]*w1.w;
        }
        #pragma unroll
        for (int u = 0; u < 4; ++u) {
            #pragma unroll
            for (int off = 32; off >= 1; off >>= 1) v[u] += __shfl_down(v[u], off, 64);
        }
        if (lane == 0) {
            #pragma unroll
            for (int u = 0; u < 4; ++u) {
                const int j = wave * 64 + i0 + u;
                float a = v[u] + br1[j];
                hbuf[j] = 0.5f * a * (1.0f + erff(a * 0.70710678118654752440f));
            }
        }
    }
    __syncthreads();

    if (t < Ez) {
        const float* w = Wr2 + (size_t)t * Hz;
        float a = br2[t];
        for (int j = 0; j < Hz; ++j) a = fmaf(hbuf[j], w[j], a);
        lg[t] = a;
    }
    __syncthreads();

    if (t == 0) {
        float mx = lg[0];
        for (int e = 1; e < Ez; ++e) mx = fmaxf(mx, lg[e]);
        float p[Ez], ssum = 0.0f;
        for (int e = 0; e < Ez; ++e) { p[e] = expf(lg[e] - mx); ssum += p[e]; }
        const float inv = 1.0f / ssum;
        for (int e = 0; e < Ez; ++e) { p[e] *= inv; probs_out[b * Ez + e] = p[e]; }
        int i0 = 0;
        for (int e = 1; e < Ez; ++e) if (p[e] > p[i0]) i0 = e;
        int i1 = (i0 == 0) ? 1 : 0;
        for (int e = 0; e < Ez; ++e) if (e != i0 && p[e] > p[i1]) i1 = e;
        float s2 = p[i0] + p[i1];
        if (s2 < 1e-6f) s2 = 1e-6f;
        tki[b * 2] = i0; tki[b * 2 + 1] = i1;
        tkw[b * 2] = p[i0] / s2; tkw[b * 2 + 1] = p[i1] / s2;
    }
}

// ===================== combine (+split-K reduce when PART) =====================
template <bool PART>
__global__ __launch_bounds__(256)
void combine_kernel(const float* __restrict__ part, const float* __restrict__ C,
                    const float* __restrict__ bb, const float* __restrict__ loraB,
                    const int* __restrict__ tki, const float* __restrict__ tkw,
                    float* __restrict__ out)
{
    const int m = blockIdx.x;
    const int t = threadIdx.x;
    const int b = m / Vz;
    const int e0 = tki[b * 2], e1 = tki[b * 2 + 1];
    const float w0 = tkw[b * 2], w1 = tkw[b * 2 + 1];

    __shared__ float lw[2 * Rz];
    if (t < 2 * Rz) {
        const int e = (t < Rz) ? e0 : e1;
        const size_t off = (size_t)m * Nz + OUTz + e * Rz + (t & (Rz - 1));
        float v = 0.0f;
        if (PART) {
            #pragma unroll
            for (int ss = 0; ss < SPLIT; ++ss) v += part[(size_t)ss * Mz * Nz + off];
        } else v = C[off];
        lw[t] = v;
    }
    __syncthreads();

    for (int o = t; o < OUTz; o += 256) {
        float acc = bb[o];
        if (PART) {
            #pragma unroll
            for (int ss = 0; ss < SPLIT; ++ss)
                acc += part[(size_t)ss * Mz * Nz + (size_t)m * Nz + o];
        } else acc += C[(size_t)m * Nz + o];
        const float* B0 = loraB + ((size_t)e0 * OUTz + o) * Rz;
        const float* B1 = loraB + ((size_t)e1 * OUTz + o) * Rz;
        float d0 = 0.0f, d1 = 0.0f;
        #pragma unroll
        for (int rr = 0; rr < Rz; ++rr) {
            d0 = fmaf(lw[rr], B0[rr], d0);
            d1 = fmaf(lw[Rz + rr], B1[rr], d1);
        }
        out[(size_t)m * OUTz + o] = acc + w0 * d0 + w1 * d1;
    }
}

// ===================== launch =====================
extern "C" void kernel_launch(void* const* d_in, const int* in_sizes, int n_in,
                              void* d_out, int out_size, void* d_ws, size_t ws_size,
                              hipStream_t stream)
{
    const float* x   = (const float*)d_in[0];
    const float* Wb  = (const float*)d_in[1];
    const float* bb  = (const float*)d_in[2];
    const float* Wr1 = (const float*)d_in[3];
    const float* br1 = (const float*)d_in[4];
    const float* Wr2 = (const float*)d_in[5];
    const float* br2 = (const float*)d_in[6];
    const float* lA  = (const float*)d_in[7];
    const float* lB  = (const float*)d_in[8];
    float* out = (float*)d_out;

    const size_t part_elems = (size_t)SPLIT * Mz * Nz;          // 9.1M floats
    const size_t need = (part_elems + Bz * Dz + 256) * sizeof(float);
    const bool use_part = (ws_size >= need);                    // ws_size is constant

    if (use_part) {
        float* part   = (float*)d_ws;
        float* pooled = part + part_elems;
        int*   tki    = (int*)(pooled + Bz * Dz);
        float* tkw    = (float*)(tki + 2 * Bz);

        (void)hipMemsetAsync(pooled, 0, Bz * Dz * sizeof(float), stream);

        gemm_pool_kernel<true><<<dim3(7 * 6 * SPLIT), 256, 0, stream>>>(
            x, Wb, lA, part, nullptr, pooled);
        router_kernel<<<Bz, 256, 0, stream>>>(pooled, Wr1, br1, Wr2, br2,
                                              out + (size_t)Mz * OUTz, tki, tkw);
        combine_kernel<true><<<Mz, 256, 0, stream>>>(part, nullptr, bb, lB, tki, tkw, out);
    } else {
        float* C      = (float*)d_ws;
        float* pooled = C + (size_t)Mz * Nz;
        int*   tki    = (int*)(pooled + Bz * Dz);
        float* tkw    = (float*)(tki + 2 * Bz);

        (void)hipMemsetAsync(d_ws, 0, ((size_t)Mz * Nz + Bz * Dz) * sizeof(float), stream);

        gemm_pool_kernel<false><<<dim3(7 * 6 * SPLIT), 256, 0, stream>>>(
            x, Wb, lA, nullptr, C, pooled);
        router_kernel<<<Bz, 256, 0, stream>>>(pooled, Wr1, br1, Wr2, br2,
                                              out + (size_t)Mz * OUTz, tki, tkw);
        combine_kernel<false><<<Mz, 256, 0, stream>>>(nullptr, C, bb, lB, tki, tkw, out);
    }
}